// Round 11
// baseline (132.630 us; speedup 1.0000x reference)
//
#include <hip/hip_runtime.h>
#include <math.h>

#define B_   2
#define NQ_  10000
#define NV_  21760
#define EMB  256
#define MQ   (B_*NQ_)   // 20000
#define MV   (B_*NV_)   // 43520

typedef short bf16x8 __attribute__((ext_vector_type(8)));
typedef float f32x4  __attribute__((ext_vector_type(4)));

__device__ constexpr int LSc[4] = {0, 16384, 20480, 21504};

__device__ __forceinline__ unsigned short f2bf(float x) {
  unsigned u = __builtin_bit_cast(unsigned, x);
  u += 0x7FFFu + ((u >> 16) & 1u);
  return (unsigned short)(u >> 16);
}
__device__ __forceinline__ float bf2f(unsigned short s) {
  return __builtin_bit_cast(float, (unsigned)s << 16);
}

// ---------------------------------------------------------------------------
// Weight prep (as before).
// ---------------------------------------------------------------------------
__global__ __launch_bounds__(256) void prep_weights(
    const float* __restrict__ Wv, const float* __restrict__ Wattn,
    const float* __restrict__ Woff, const float* __restrict__ Wout,
    unsigned short* __restrict__ WvT, unsigned short* __restrict__ WoutT,
    unsigned short* __restrict__ WqHi, unsigned short* __restrict__ WqLo) {
  int n = blockIdx.x;       // 0..895
  int k = threadIdx.x;      // 0..255
  if (n < 256) {
    WvT[n * 256 + k] = f2bf(Wv[k * 256 + n]);
  } else if (n < 512) {
    int c = n - 256;
    WoutT[c * 256 + k] = f2bf(Wout[k * 256 + c]);
  } else {
    int qr = n - 512;       // 0..383
    float x = (qr < 256) ? Woff[k * 256 + qr] : Wattn[k * 128 + (qr - 256)];
    unsigned short hi = f2bf(x);
    WqHi[qr * 256 + k] = hi;
    WqLo[qr * 256 + k] = f2bf(x - bf2f(hi));
  }
}

// ---------------------------------------------------------------------------
// MFMA GEMM. 128x128 tile, BK=32, 4 waves (2x2), 4x4 16x16x32 frags/wave.
// LDS XOR-swizzled (<=2-way on staging writes and ds_read_b128).
// MODE 0: A bf16, 1-term.   MODE 1: A fp32 (cvt in staging), 1-term.
// MODE 3: A fp32 split hi/lo in staging; 3-term for col0<256 (off cols),
//         1-term for col0>=256 (attn cols). Dual output C / C2.
// VPERM:  epilogue assembles the x-pair-packed bf16 v tile in LDS (32 KB)
//         then writes coalesced. Pair-block layout (1024 B = 2 pixels):
//         byte = h*128 + (d>>3)*32 + (x&1)*16 + (d&7)*2.
// ---------------------------------------------------------------------------
template <int MODE, typename OutT, bool VPERM = false>
__global__ __launch_bounds__(256) void gemm_mfma(
    const void* __restrict__ Aa,
    const unsigned short* __restrict__ Bt, const unsigned short* __restrict__ Bt2,
    const float* __restrict__ bias, const float* __restrict__ bias2,
    OutT* __restrict__ C, float* __restrict__ C2, int M, int N) {
  constexpr int BM = 128, BK = 32;
  constexpr int SMEM_SHORTS = (MODE == 3 || VPERM) ? 16384 : 8192;
  __shared__ unsigned short smem[SMEM_SHORTS];
  unsigned short* As  = smem;                 // BM*BK
  unsigned short* Bs  = smem + ((MODE == 3) ? 2 : 1) * BM * BK;
  unsigned short* As2 = smem + BM * BK;       // MODE3 only
  unsigned short* Bs2 = smem + 3 * BM * BK;   // MODE3 only

  const int tid = threadIdx.x;
  const int lane = tid & 63, wv = tid >> 6;
  const int wr = wv >> 1, wc = wv & 1;
  const int row0 = blockIdx.x * BM, col0 = blockIdx.y * BM;

  auto lds_addr = [](int row, int kslot) -> int {
    return row * 64 + ((kslot ^ ((row >> 1) & 3)) << 4);
  };

  auto stage_bf = [&](unsigned short* dst, const unsigned short* src,
                      int rbase, int rmax, int kk) {
#pragma unroll
    for (int i = 0; i < 2; ++i) {
      int idx = tid + 256 * i;
      int row = idx >> 2, ks = idx & 3;
      int rg = min(rbase + row, rmax);
      bf16x8 vdat = *(const bf16x8*)(src + (size_t)rg * 256 + kk + ks * 8);
      *(bf16x8*)((char*)dst + lds_addr(row, ks)) = vdat;
    }
  };
  auto stage_cvt = [&](unsigned short* dst, const float* src,
                       int rbase, int rmax, int kk) {
#pragma unroll
    for (int i = 0; i < 4; ++i) {
      int idx = tid + 256 * i;
      int row = idx >> 3, c4 = idx & 7;
      int rg = min(rbase + row, rmax);
      float4 vdat = *(const float4*)(src + (size_t)rg * 256 + kk + c4 * 4);
      ushort4 o;
      o.x = f2bf(vdat.x); o.y = f2bf(vdat.y);
      o.z = f2bf(vdat.z); o.w = f2bf(vdat.w);
      *(ushort4*)((char*)dst + lds_addr(row, c4 >> 1) + (c4 & 1) * 8) = o;
    }
  };
  auto stage_cvt2 = [&](unsigned short* dstH, unsigned short* dstL,
                        const float* src, int rbase, int rmax, int kk) {
#pragma unroll
    for (int i = 0; i < 4; ++i) {
      int idx = tid + 256 * i;
      int row = idx >> 3, c4 = idx & 7;
      int rg = min(rbase + row, rmax);
      float4 vdat = *(const float4*)(src + (size_t)rg * 256 + kk + c4 * 4);
      ushort4 hh, ll;
      hh.x = f2bf(vdat.x); ll.x = f2bf(vdat.x - bf2f(hh.x));
      hh.y = f2bf(vdat.y); ll.y = f2bf(vdat.y - bf2f(hh.y));
      hh.z = f2bf(vdat.z); ll.z = f2bf(vdat.z - bf2f(hh.z));
      hh.w = f2bf(vdat.w); ll.w = f2bf(vdat.w - bf2f(hh.w));
      int a = lds_addr(row, c4 >> 1) + (c4 & 1) * 8;
      *(ushort4*)((char*)dstH + a) = hh;
      *(ushort4*)((char*)dstL + a) = ll;
    }
  };

  const bool three_term = (MODE == 3) && (col0 < 256);

  f32x4 acc[4][4] = {};

  for (int kk = 0; kk < 256; kk += BK) {
    if (kk) __syncthreads();
    if constexpr (MODE == 1)
      stage_cvt(As, (const float*)Aa, row0, M - 1, kk);
    else if constexpr (MODE == 3) {
      if (three_term)
        stage_cvt2(As, As2, (const float*)Aa, row0, M - 1, kk);
      else
        stage_cvt(As, (const float*)Aa, row0, M - 1, kk);
    } else
      stage_bf(As, (const unsigned short*)Aa, row0, M - 1, kk);
    stage_bf(Bs, Bt, col0, N - 1, kk);
    if constexpr (MODE == 3)
      if (three_term) stage_bf(Bs2, Bt2, col0, N - 1, kk);
    __syncthreads();

    const int kslot = lane >> 4;
    bf16x8 af[4], bfr[4];
#pragma unroll
    for (int i = 0; i < 4; ++i) {
      int ra = wr * 64 + i * 16 + (lane & 15);
      af[i] = *(const bf16x8*)((const char*)As + lds_addr(ra, kslot));
      int rb = wc * 64 + i * 16 + (lane & 15);
      bfr[i] = *(const bf16x8*)((const char*)Bs + lds_addr(rb, kslot));
    }
#pragma unroll
    for (int mi = 0; mi < 4; ++mi)
#pragma unroll
      for (int ni = 0; ni < 4; ++ni)
        acc[mi][ni] = __builtin_amdgcn_mfma_f32_16x16x32_bf16(
            af[mi], bfr[ni], acc[mi][ni], 0, 0, 0);

    if constexpr (MODE == 3) {
      if (three_term) {
        bf16x8 af2[4], bfr2[4];
#pragma unroll
        for (int i = 0; i < 4; ++i) {
          int ra = wr * 64 + i * 16 + (lane & 15);
          af2[i] = *(const bf16x8*)((const char*)As2 + lds_addr(ra, kslot));
          int rb = wc * 64 + i * 16 + (lane & 15);
          bfr2[i] = *(const bf16x8*)((const char*)Bs2 + lds_addr(rb, kslot));
        }
#pragma unroll
        for (int mi = 0; mi < 4; ++mi)
#pragma unroll
          for (int ni = 0; ni < 4; ++ni) {
            acc[mi][ni] = __builtin_amdgcn_mfma_f32_16x16x32_bf16(
                af2[mi], bfr[ni], acc[mi][ni], 0, 0, 0);
            acc[mi][ni] = __builtin_amdgcn_mfma_f32_16x16x32_bf16(
                af[mi], bfr2[ni], acc[mi][ni], 0, 0, 0);
          }
      }
    }
  }

  // epilogue: D frag layout col=lane&15, row=(lane>>4)*4+reg  [m89-verified]
  if constexpr (VPERM) {
    float bb4[4];
#pragma unroll
    for (int ni = 0; ni < 4; ++ni)
      bb4[ni] = bias[col0 + wc * 64 + ni * 16 + (lane & 15)];
    __syncthreads();                 // As/Bs dead; reuse full 32 KB
    unsigned short* pbuf = smem;
#pragma unroll
    for (int mi = 0; mi < 4; ++mi) {
#pragma unroll
      for (int r = 0; r < 4; ++r) {
        int lr = wr * 64 + mi * 16 + ((lane >> 4) << 2) + r;  // local row
        int pb = lr >> 1, par = lr & 1;
#pragma unroll
        for (int ni = 0; ni < 4; ++ni) {
          int lcol = wc * 64 + ni * 16 + (lane & 15);
          float val = acc[mi][ni][r] + bb4[ni];
          int hl = lcol >> 5, d = lcol & 31;
          int off = pb * 512 + hl * 128 + ((d >> 3) << 5) + (par << 4) +
                    ((d & 7) << 1);
          *(unsigned short*)((char*)pbuf + off) = f2bf(val);
        }
      }
    }
    __syncthreads();
    // coalesced write-out: 64 pair-blocks x 512 B (our 4 heads)
    int pix0 = row0, bb2 = 0;
    if (pix0 >= NV_) { bb2 = 1; pix0 -= NV_; }
    int lvl = (pix0 >= 16384) + (pix0 >= 20480) + (pix0 >= 21504);
    int rel0 = pix0 - LSc[lvl];
    char* dst = (char*)C + ((size_t)bb2 * NV_ + LSc[lvl]) * 512 +
                (size_t)(rel0 >> 1) * 1024 + (size_t)(col0 >> 5) * 128;
    int pb = tid >> 2, q = tid & 3;
#pragma unroll
    for (int i = 0; i < 8; ++i) {
      int u = q * 16 + i * 64;
      uint4 vd = *(const uint4*)((const char*)pbuf + pb * 512 + u);
      *(uint4*)(dst + (size_t)pb * 1024 + u) = vd;
    }
  } else {
#pragma unroll
    for (int ni = 0; ni < 4; ++ni) {
      int gcol = col0 + wc * 64 + ni * 16 + (lane & 15);
      float bb = (MODE == 3 && gcol >= 256) ? bias2[gcol - 256] : bias[gcol];
#pragma unroll
      for (int mi = 0; mi < 4; ++mi) {
        int rowbase = row0 + wr * 64 + mi * 16 + ((lane >> 4) << 2);
        f32x4 a = acc[mi][ni];
#pragma unroll
        for (int r = 0; r < 4; ++r) {
          int row = rowbase + r;
          if (row < M) {
            float val = a[r] + bb;
            if constexpr (MODE == 3) {
              if (gcol >= 256)
                C2[(size_t)row * 128 + (gcol - 256)] = val;
              else
                C[(size_t)row * 256 + gcol] = (OutT)val;
            } else if constexpr (sizeof(OutT) == 2) {
              C[(size_t)row * N + gcol] = (OutT)f2bf(val);
            } else {
              C[(size_t)row * N + gcol] = (OutT)val;
            }
          }
        }
      }
    }
  }
}

// ---------------------------------------------------------------------------
// Sampling v8: 512-thread block = 4 queries x 2 waves; wave w owns levels
// {2w,2w+1}. Lane = (pslot = lane>>5, h = (lane>>2)&7, cq = lane&3); each
// lane gathers 16 B (8 channels) per corner -> gather instrs halved vs v7.
// Phase 1: one (h,l,p) combo per lane -> skewed 32-B slot (4 byte-offsets
// pairidx<<10 | (x&1)<<4, + 4 weights). Phase 2: per level, 2 point-iters
// (p = piter*2+pslot), 4 x 16-B gathers each. Phase 3: shfl_xor(32) merges
// pslot pairs, LDS merges wave pairs, uint4 bf16 store.
// ---------------------------------------------------------------------------
__global__ __launch_bounds__(512) void msda_sample8(
    const char* __restrict__ v,            // 16B-parity pair-packed bf16
    const float* __restrict__ off,         // (MQ, 256)
    const float* __restrict__ attnlg,      // (MQ, 128)
    uint4* __restrict__ tmp4) {            // (MQ, 256ch) bf16
  __shared__ unsigned coeff[4 * 136 * 8];   // 17408 B; 4 KB reused in phase 3
  const int tid = threadIdx.x;
  const int lane = tid & 63;
  const int wid = tid >> 6;        // 0..7
  const int wq = wid >> 1;         // query-in-block 0..3
  const int w = wid & 1;           // level-half
  const int bq = blockIdx.x * 4 + wq;
  const int b = (blockIdx.x * 4) / NQ_;   // block-uniform

  unsigned* cbase = coeff + wq * (136 * 8);
  const float* offq = off + (size_t)bq * 256;
  const float* attq = attnlg + (size_t)bq * 128;

  // ---- phase 1: one combo per lane (covers this wave's 2 levels)
  {
    int h = lane >> 3, dl = (lane >> 2) & 1, p = lane & 3;
    int l = 2 * w + dl;
    int Wl = 128 >> l, sh = 7 - l;

    const float* lg = attq + h * 16 + l * 4;
    float l0 = lg[0], l1 = lg[1], l2 = lg[2], l3 = lg[3];
    float m = fmaxf(fmaxf(l0, l1), fmaxf(l2, l3));
    float e0 = expf(l0 - m), e1 = expf(l1 - m);
    float e2 = expf(l2 - m), e3 = expf(l3 - m);
    float ep = (p == 0) ? e0 : (p == 1) ? e1 : (p == 2) ? e2 : e3;
    float wsm = ep / (e0 + e1 + e2 + e3);

    float gx = offq[h * 32 + (l * 4 + p) * 2 + 0];
    float gy = offq[h * 32 + (l * 4 + p) * 2 + 1];
    float s = 0.5f * (float)(Wl - 1);
    float px = fmaf(gx, s, s), py = fmaf(gy, s, s);
    float x0f = floorf(px), y0f = floorf(py);
    float wx = px - x0f, wy = py - y0f;
    int x0 = (int)x0f, y0 = (int)y0f;

    bool bx0 = (unsigned)x0 < (unsigned)Wl, bx1 = (unsigned)(x0 + 1) < (unsigned)Wl;
    bool by0 = (unsigned)y0 < (unsigned)Wl, by1 = (unsigned)(y0 + 1) < (unsigned)Wl;
    int x0c = min(max(x0, 0), Wl - 1), x1c = min(max(x0 + 1, 0), Wl - 1);
    int y0c = min(max(y0, 0), Wl - 1), y1c = min(max(y0 + 1, 0), Wl - 1);

    auto poff = [&](int xx, int yy) -> unsigned {
      return ((unsigned)((yy << (sh - 1)) + (xx >> 1)) << 10) |
             ((unsigned)(xx & 1) << 4);
    };

    float wxm = 1.f - wx, wym = 1.f - wy;
    float w00 = (bx0 & by0) ? wsm * wxm * wym : 0.f;
    float w01 = (bx1 & by0) ? wsm * wx  * wym : 0.f;
    float w10 = (bx0 & by1) ? wsm * wxm * wy  : 0.f;
    float w11 = (bx1 & by1) ? wsm * wx  * wy  : 0.f;

    unsigned* slot = cbase + ((h * 17 + l * 4 + p)) * 8;
    uint4 s0;
    s0.x = poff(x0c, y0c);
    s0.y = poff(x1c, y0c);
    s0.z = poff(x0c, y1c);
    s0.w = poff(x1c, y1c);
    *(uint4*)slot = s0;
    uint4 s1;
    s1.x = __builtin_bit_cast(unsigned, w00);
    s1.y = __builtin_bit_cast(unsigned, w01);
    s1.z = __builtin_bit_cast(unsigned, w10);
    s1.w = __builtin_bit_cast(unsigned, w11);
    *(uint4*)(slot + 4) = s1;
  }
  __syncthreads();

  // ---- phase 2: this wave's two levels, 2 points per iteration (pslot)
  const int pslot = lane >> 5;
  const int h = (lane >> 2) & 7;
  const int cq = lane & 3;
  const unsigned laneoff = (unsigned)(h * 128 + cq * 32);
  float4 a0 = make_float4(0.f, 0.f, 0.f, 0.f);   // channels cq*8 + 0..3
  float4 a1 = make_float4(0.f, 0.f, 0.f, 0.f);   // channels cq*8 + 4..7

#pragma unroll
  for (int dl = 0; dl < 2; ++dl) {
    const int l = 2 * w + dl;
    const char* lb = v + ((size_t)b * NV_ + LSc[l]) * 512;
#pragma unroll
    for (int piter = 0; piter < 2; ++piter) {
      const int p = piter * 2 + pslot;
      const unsigned* cb = cbase + (h * 17 + l * 4 + p) * 8;
      uint4 s0 = *(const uint4*)cb;
      uint4 s1 = *(const uint4*)(cb + 4);
      float w00 = __builtin_bit_cast(float, s1.x);
      float w01 = __builtin_bit_cast(float, s1.y);
      float w10 = __builtin_bit_cast(float, s1.z);
      float w11 = __builtin_bit_cast(float, s1.w);

      uint4 r00 = *(const uint4*)(lb + (laneoff + s0.x));
      uint4 r01 = *(const uint4*)(lb + (laneoff + s0.y));
      uint4 r10 = *(const uint4*)(lb + (laneoff + s0.z));
      uint4 r11 = *(const uint4*)(lb + (laneoff + s0.w));

      a0.x += w00 * __builtin_bit_cast(float, r00.x << 16)
            + w01 * __builtin_bit_cast(float, r01.x << 16)
            + w10 * __builtin_bit_cast(float, r10.x << 16)
            + w11 * __builtin_bit_cast(float, r11.x << 16);
      a0.y += w00 * __builtin_bit_cast(float, r00.x & 0xFFFF0000u)
            + w01 * __builtin_bit_cast(float, r01.x & 0xFFFF0000u)
            + w10 * __builtin_bit_cast(float, r10.x & 0xFFFF0000u)
            + w11 * __builtin_bit_cast(float, r11.x & 0xFFFF0000u);
      a0.z += w00 * __builtin_bit_cast(float, r00.y << 16)
            + w01 * __builtin_bit_cast(float, r01.y << 16)
            + w10 * __builtin_bit_cast(float, r10.y << 16)
            + w11 * __builtin_bit_cast(float, r11.y << 16);
      a0.w += w00 * __builtin_bit_cast(float, r00.y & 0xFFFF0000u)
            + w01 * __builtin_bit_cast(float, r01.y & 0xFFFF0000u)
            + w10 * __builtin_bit_cast(float, r10.y & 0xFFFF0000u)
            + w11 * __builtin_bit_cast(float, r11.y & 0xFFFF0000u);
      a1.x += w00 * __builtin_bit_cast(float, r00.z << 16)
            + w01 * __builtin_bit_cast(float, r01.z << 16)
            + w10 * __builtin_bit_cast(float, r10.z << 16)
            + w11 * __builtin_bit_cast(float, r11.z << 16);
      a1.y += w00 * __builtin_bit_cast(float, r00.z & 0xFFFF0000u)
            + w01 * __builtin_bit_cast(float, r01.z & 0xFFFF0000u)
            + w10 * __builtin_bit_cast(float, r10.z & 0xFFFF0000u)
            + w11 * __builtin_bit_cast(float, r11.z & 0xFFFF0000u);
      a1.z += w00 * __builtin_bit_cast(float, r00.w << 16)
            + w01 * __builtin_bit_cast(float, r01.w << 16)
            + w10 * __builtin_bit_cast(float, r10.w << 16)
            + w11 * __builtin_bit_cast(float, r11.w << 16);
      a1.w += w00 * __builtin_bit_cast(float, r00.w & 0xFFFF0000u)
            + w01 * __builtin_bit_cast(float, r01.w & 0xFFFF0000u)
            + w10 * __builtin_bit_cast(float, r10.w & 0xFFFF0000u)
            + w11 * __builtin_bit_cast(float, r11.w & 0xFFFF0000u);
    }
  }

  // ---- phase 3: merge pslot pairs (shfl), then wave pairs (LDS)
  a0.x += __shfl_xor(a0.x, 32); a0.y += __shfl_xor(a0.y, 32);
  a0.z += __shfl_xor(a0.z, 32); a0.w += __shfl_xor(a0.w, 32);
  a1.x += __shfl_xor(a1.x, 32); a1.y += __shfl_xor(a1.y, 32);
  a1.z += __shfl_xor(a1.z, 32); a1.w += __shfl_xor(a1.w, 32);

  __syncthreads();
  float4* red = (float4*)coeff;    // 4 q x 32 lanes x 32 B = 4096 B
  if (w == 1 && lane < 32) {
    red[(wq * 32 + lane) * 2 + 0] = a0;
    red[(wq * 32 + lane) * 2 + 1] = a1;
  }
  __syncthreads();
  if (w == 0 && lane < 32) {
    float4 o0 = red[(wq * 32 + lane) * 2 + 0];
    float4 o1 = red[(wq * 32 + lane) * 2 + 1];
    a0.x += o0.x; a0.y += o0.y; a0.z += o0.z; a0.w += o0.w;
    a1.x += o1.x; a1.y += o1.y; a1.z += o1.z; a1.w += o1.w;
    uint4 o;
    o.x = (unsigned)f2bf(a0.x) | ((unsigned)f2bf(a0.y) << 16);
    o.y = (unsigned)f2bf(a0.z) | ((unsigned)f2bf(a0.w) << 16);
    o.z = (unsigned)f2bf(a1.x) | ((unsigned)f2bf(a1.y) << 16);
    o.w = (unsigned)f2bf(a1.z) | ((unsigned)f2bf(a1.w) << 16);
    *(uint4*)((char*)tmp4 + (size_t)bq * 512 + h * 64 + cq * 16) = o;
  }
}

// ---------------------------------------------------------------------------
extern "C" void kernel_launch(void* const* d_in, const int* in_sizes, int n_in,
                              void* d_out, int out_size, void* d_ws, size_t ws_size,
                              hipStream_t stream) {
  const float* query  = (const float*)d_in[0];
  // d_in[1] = key (unused)
  const float* value  = (const float*)d_in[2];
  const float* W_off  = (const float*)d_in[3];
  const float* b_off  = (const float*)d_in[4];
  const float* W_attn = (const float*)d_in[5];
  const float* b_attn = (const float*)d_in[6];
  const float* W_v    = (const float*)d_in[7];
  const float* b_v    = (const float*)d_in[8];
  const float* W_out  = (const float*)d_in[9];
  const float* b_out  = (const float*)d_in[10];
  float* out = (float*)d_out;

  char* p = (char*)d_ws;
  unsigned short* v_bf  = (unsigned short*)p; p += (size_t)MV * 256 * 2;   // 22.3 MB
  float*          off_w = (float*)p;          p += (size_t)MQ * 256 * 4;   // 20.5 MB
  float*          att_w = (float*)p;          p += (size_t)MQ * 128 * 4;   // 10.2 MB
  unsigned short* tmp_bf= (unsigned short*)p; p += (size_t)MQ * 256 * 2;   // 10.2 MB
  unsigned short* WvT   = (unsigned short*)p; p += 256 * 256 * 2;
  unsigned short* WoutT = (unsigned short*)p; p += 256 * 256 * 2;
  unsigned short* WqHi  = (unsigned short*)p; p += 384 * 256 * 2;
  unsigned short* WqLo  = (unsigned short*)p; p += 384 * 256 * 2;

  prep_weights<<<dim3(896), dim3(256), 0, stream>>>(
      W_v, W_attn, W_off, W_out, WvT, WoutT, WqHi, WqLo);

  // v = value @ W_v + b_v  (bf16, 16B-parity pair-packed, LDS-coalesced out)
  gemm_mfma<1, unsigned short, true><<<dim3(MV / 128, 2), dim3(256), 0, stream>>>(
      value, WvT, nullptr, b_v, nullptr, v_bf, nullptr, MV, 256);

  // fused q projections: cols 0-255 -> off (3-term), 256-383 -> attn (1-term)
  gemm_mfma<3, float><<<dim3((MQ + 127) / 128, 3), dim3(256), 0, stream>>>(
      query, WqHi, WqLo, b_off, b_attn, off_w, att_w, MQ, 384);

  // bilinear sampling + softmax-weighted accumulation (2 waves / query)
  msda_sample8<<<dim3(MQ / 4), dim3(512), 0, stream>>>(
      (const char*)v_bf, off_w, att_w, (uint4*)tmp_bf);

  // out = tmp @ W_out + b_out
  gemm_mfma<0, float><<<dim3((MQ + 127) / 128, 2), dim3(256), 0, stream>>>(
      tmp_bf, WoutT, nullptr, b_out, nullptr, out, nullptr, MQ, 256);
}

// Round 12
// 125.320 us; speedup vs baseline: 1.0583x; 1.0583x over previous
//
#include <hip/hip_runtime.h>
#include <math.h>

#define B_   2
#define NQ_  10000
#define NV_  21760
#define EMB  256
#define MQ   (B_*NQ_)   // 20000
#define MV   (B_*NV_)   // 43520

typedef short bf16x8 __attribute__((ext_vector_type(8)));
typedef float f32x4  __attribute__((ext_vector_type(4)));

__device__ constexpr int LSc[4] = {0, 16384, 20480, 21504};

__device__ __forceinline__ unsigned short f2bf(float x) {
  unsigned u = __builtin_bit_cast(unsigned, x);
  u += 0x7FFFu + ((u >> 16) & 1u);
  return (unsigned short)(u >> 16);
}
__device__ __forceinline__ float bf2f(unsigned short s) {
  return __builtin_bit_cast(float, (unsigned)s << 16);
}

// ---------------------------------------------------------------------------
// Weight prep (as before).
// ---------------------------------------------------------------------------
__global__ __launch_bounds__(256) void prep_weights(
    const float* __restrict__ Wv, const float* __restrict__ Wattn,
    const float* __restrict__ Woff, const float* __restrict__ Wout,
    unsigned short* __restrict__ WvT, unsigned short* __restrict__ WoutT,
    unsigned short* __restrict__ WqHi, unsigned short* __restrict__ WqLo) {
  int n = blockIdx.x;       // 0..895
  int k = threadIdx.x;      // 0..255
  if (n < 256) {
    WvT[n * 256 + k] = f2bf(Wv[k * 256 + n]);
  } else if (n < 512) {
    int c = n - 256;
    WoutT[c * 256 + k] = f2bf(Wout[k * 256 + c]);
  } else {
    int qr = n - 512;       // 0..383
    float x = (qr < 256) ? Woff[k * 256 + qr] : Wattn[k * 128 + (qr - 256)];
    unsigned short hi = f2bf(x);
    WqHi[qr * 256 + k] = hi;
    WqLo[qr * 256 + k] = f2bf(x - bf2f(hi));
  }
}

// ---------------------------------------------------------------------------
// MFMA GEMM (R10 structure). 128x128 tile, BK=32, 4 waves (2x2), 4x4 frags.
// bf16 staging now uses global_load_lds width-16: LDS dest LINEAR
// (wave-uniform base + lane*16), global source pre-swizzled (ks ^ xorb) so
// the swizzled ds_read_b128 side (slot kslot^x) is unchanged  [rule #21].
// MODE 0: A bf16, 1-term.   MODE 1: A fp32 (cvt in staging), 1-term.
// MODE 3: A fp32 split hi/lo in staging; 3-term for col0<256 (off cols),
//         1-term for col0>=256 (attn cols). Dual output C / C2.
// VPERM:  epilogue scatters bf16 into the x-pair-packed v layout:
//         byte = (b*NV+LS[l])*512 + ((y*(W/2)+x/2)<<10) + ((x&1)<<3)
//                + h*128 + (d>>2)*16 + (d&3)*2
// ---------------------------------------------------------------------------
template <int MODE, typename OutT, bool VPERM = false>
__global__ __launch_bounds__(256) void gemm_mfma(
    const void* __restrict__ Aa,
    const unsigned short* __restrict__ Bt, const unsigned short* __restrict__ Bt2,
    const float* __restrict__ bias, const float* __restrict__ bias2,
    OutT* __restrict__ C, float* __restrict__ C2, int M, int N) {
  constexpr int BM = 128, BK = 32;
  __shared__ unsigned short As[(MODE == 3 ? 2 : 1) * BM * BK];
  __shared__ unsigned short Bs[(MODE == 3 ? 2 : 1) * BM * BK];
  unsigned short* As2 = As + BM * BK;
  unsigned short* Bs2 = Bs + BM * BK;

  const int tid = threadIdx.x;
  const int lane = tid & 63, wv = tid >> 6;
  const int wr = wv >> 1, wc = wv & 1;
  const int row0 = blockIdx.x * BM, col0 = blockIdx.y * BM;

  auto lds_addr = [](int row, int kslot) -> int {
    return row * 64 + ((kslot ^ ((row >> 1) & 3)) << 4);
  };

  // bf16 staging via global_load_lds(16B): linear LDS dest, pre-swizzled src.
  auto stage_bf = [&](unsigned short* dst, const unsigned short* src,
                      int rbase, int rmax, int kk) {
#pragma unroll
    for (int i = 0; i < 2; ++i) {
      int idx = tid + 256 * i;
      int row = idx >> 2, ks = idx & 3;
      int rg = min(rbase + row, rmax);
      int xorb = (row >> 1) & 3;
      const unsigned short* gp =
          src + (size_t)rg * 256 + kk + ((ks ^ xorb) << 3);
      unsigned short* lp = dst + (size_t)(wv * 64 + i * 256) * 8;
      __builtin_amdgcn_global_load_lds(
          (const __attribute__((address_space(1))) void*)gp,
          (__attribute__((address_space(3))) void*)lp, 16, 0, 0);
    }
  };
  auto stage_cvt = [&](unsigned short* dst, const float* src,
                       int rbase, int rmax, int kk) {
#pragma unroll
    for (int i = 0; i < 4; ++i) {
      int idx = tid + 256 * i;
      int row = idx >> 3, c4 = idx & 7;
      int rg = min(rbase + row, rmax);
      float4 vdat = *(const float4*)(src + (size_t)rg * 256 + kk + c4 * 4);
      ushort4 o;
      o.x = f2bf(vdat.x); o.y = f2bf(vdat.y);
      o.z = f2bf(vdat.z); o.w = f2bf(vdat.w);
      *(ushort4*)((char*)dst + lds_addr(row, c4 >> 1) + (c4 & 1) * 8) = o;
    }
  };
  auto stage_cvt2 = [&](unsigned short* dstH, unsigned short* dstL,
                        const float* src, int rbase, int rmax, int kk) {
#pragma unroll
    for (int i = 0; i < 4; ++i) {
      int idx = tid + 256 * i;
      int row = idx >> 3, c4 = idx & 7;
      int rg = min(rbase + row, rmax);
      float4 vdat = *(const float4*)(src + (size_t)rg * 256 + kk + c4 * 4);
      ushort4 hh, ll;
      hh.x = f2bf(vdat.x); ll.x = f2bf(vdat.x - bf2f(hh.x));
      hh.y = f2bf(vdat.y); ll.y = f2bf(vdat.y - bf2f(hh.y));
      hh.z = f2bf(vdat.z); ll.z = f2bf(vdat.z - bf2f(hh.z));
      hh.w = f2bf(vdat.w); ll.w = f2bf(vdat.w - bf2f(hh.w));
      int a = lds_addr(row, c4 >> 1) + (c4 & 1) * 8;
      *(ushort4*)((char*)dstH + a) = hh;
      *(ushort4*)((char*)dstL + a) = ll;
    }
  };

  const bool three_term = (MODE == 3) && (col0 < 256);

  f32x4 acc[4][4] = {};

  for (int kk = 0; kk < 256; kk += BK) {
    if (kk) __syncthreads();
    if constexpr (MODE == 1)
      stage_cvt(As, (const float*)Aa, row0, M - 1, kk);
    else if constexpr (MODE == 3) {
      if (three_term)
        stage_cvt2(As, As2, (const float*)Aa, row0, M - 1, kk);
      else
        stage_cvt(As, (const float*)Aa, row0, M - 1, kk);
    } else
      stage_bf(As, (const unsigned short*)Aa, row0, M - 1, kk);
    stage_bf(Bs, Bt, col0, N - 1, kk);
    if constexpr (MODE == 3)
      if (three_term) stage_bf(Bs2, Bt2, col0, N - 1, kk);
    __syncthreads();

    const int kslot = lane >> 4;
    bf16x8 af[4], bfr[4];
#pragma unroll
    for (int i = 0; i < 4; ++i) {
      int ra = wr * 64 + i * 16 + (lane & 15);
      af[i] = *(const bf16x8*)((const char*)As + lds_addr(ra, kslot));
      int rb = wc * 64 + i * 16 + (lane & 15);
      bfr[i] = *(const bf16x8*)((const char*)Bs + lds_addr(rb, kslot));
    }
#pragma unroll
    for (int mi = 0; mi < 4; ++mi)
#pragma unroll
      for (int ni = 0; ni < 4; ++ni)
        acc[mi][ni] = __builtin_amdgcn_mfma_f32_16x16x32_bf16(
            af[mi], bfr[ni], acc[mi][ni], 0, 0, 0);

    if constexpr (MODE == 3) {
      if (three_term) {
        bf16x8 af2[4], bfr2[4];
#pragma unroll
        for (int i = 0; i < 4; ++i) {
          int ra = wr * 64 + i * 16 + (lane & 15);
          af2[i] = *(const bf16x8*)((const char*)As2 + lds_addr(ra, kslot));
          int rb = wc * 64 + i * 16 + (lane & 15);
          bfr2[i] = *(const bf16x8*)((const char*)Bs2 + lds_addr(rb, kslot));
        }
#pragma unroll
        for (int mi = 0; mi < 4; ++mi)
#pragma unroll
          for (int ni = 0; ni < 4; ++ni) {
            acc[mi][ni] = __builtin_amdgcn_mfma_f32_16x16x32_bf16(
                af2[mi], bfr[ni], acc[mi][ni], 0, 0, 0);
            acc[mi][ni] = __builtin_amdgcn_mfma_f32_16x16x32_bf16(
                af[mi], bfr2[ni], acc[mi][ni], 0, 0, 0);
          }
      }
    }
  }

  // epilogue: D frag layout col=lane&15, row=(lane>>4)*4+reg  [m89-verified]
  if constexpr (VPERM) {
    float bb4[4];
#pragma unroll
    for (int ni = 0; ni < 4; ++ni)
      bb4[ni] = bias[col0 + wc * 64 + ni * 16 + (lane & 15)];
#pragma unroll
    for (int mi = 0; mi < 4; ++mi) {
#pragma unroll
      for (int r = 0; r < 4; ++r) {
        int row = row0 + wr * 64 + mi * 16 + ((lane >> 4) << 2) + r;
        int pix = row, bb2 = 0;
        if (pix >= NV_) { bb2 = 1; pix -= NV_; }
        int lvl = (pix >= 16384) + (pix >= 20480) + (pix >= 21504);
        int sh = 7 - lvl;
        int rel = pix - LSc[lvl];
        int x = rel & ((1 << sh) - 1), y = rel >> sh;
        unsigned pairoff = ((unsigned)((y << (sh - 1)) + (x >> 1)) << 10) |
                           ((unsigned)(x & 1) << 3);
        char* vout = (char*)C + ((size_t)bb2 * NV_ + LSc[lvl]) * 512 + pairoff;
#pragma unroll
        for (int ni = 0; ni < 4; ++ni) {
          int gcol = col0 + wc * 64 + ni * 16 + (lane & 15);
          float val = acc[mi][ni][r] + bb4[ni];
          int h = gcol >> 5, d = gcol & 31;
          *(unsigned short*)(vout + h * 128 + (d >> 2) * 16 + (d & 3) * 2) =
              f2bf(val);
        }
      }
    }
  } else {
#pragma unroll
    for (int ni = 0; ni < 4; ++ni) {
      int gcol = col0 + wc * 64 + ni * 16 + (lane & 15);
      float bb = (MODE == 3 && gcol >= 256) ? bias2[gcol - 256] : bias[gcol];
#pragma unroll
      for (int mi = 0; mi < 4; ++mi) {
        int rowbase = row0 + wr * 64 + mi * 16 + ((lane >> 4) << 2);
        f32x4 a = acc[mi][ni];
#pragma unroll
        for (int r = 0; r < 4; ++r) {
          int row = rowbase + r;
          if (row < M) {
            float val = a[r] + bb;
            if constexpr (MODE == 3) {
              if (gcol >= 256)
                C2[(size_t)row * 128 + (gcol - 256)] = val;
              else
                C[(size_t)row * 256 + gcol] = (OutT)val;
            } else if constexpr (sizeof(OutT) == 2) {
              C[(size_t)row * N + gcol] = (OutT)f2bf(val);
            } else {
              C[(size_t)row * N + gcol] = (OutT)val;
            }
          }
        }
      }
    }
  }
}

// ---------------------------------------------------------------------------
// Sampling v7 (R10's best: 56.3 µs): 512-thread block = 4 queries x 2 waves;
// wave w owns levels {2w, 2w+1}. Phase 1: one (h,l,p) combo per lane ->
// skewed 32-B LDS slot. Phase 2: 16 x 8-B gathers per level (pair-packed
// bf16 v). Phase 3: LDS merge of the wave pair.
// ---------------------------------------------------------------------------
__global__ __launch_bounds__(512) void msda_sample7(
    const char* __restrict__ v,            // pair-packed bf16
    const float* __restrict__ off,         // (MQ, 256)
    const float* __restrict__ attnlg,      // (MQ, 128)
    ushort4* __restrict__ tmp4) {          // (MQ, 64) bf16 (h,d)
  __shared__ unsigned coeff[4 * 136 * 8];   // 17408 B; first 4 KB reused
  const int tid = threadIdx.x;
  const int lane = tid & 63;
  const int wid = tid >> 6;        // 0..7
  const int wq = wid >> 1;         // query-in-block 0..3
  const int w = wid & 1;           // level-half
  const int bq = blockIdx.x * 4 + wq;
  const int b = (blockIdx.x * 4) / NQ_;   // block-uniform

  unsigned* cbase = coeff + wq * (136 * 8);
  const float* offq = off + (size_t)bq * 256;
  const float* attq = attnlg + (size_t)bq * 128;

  // ---- phase 1: one combo per lane
  {
    int h = lane >> 3, dl = (lane >> 2) & 1, p = lane & 3;
    int l = 2 * w + dl;
    int Wl = 128 >> l, sh = 7 - l;

    const float* lg = attq + h * 16 + l * 4;
    float l0 = lg[0], l1 = lg[1], l2 = lg[2], l3 = lg[3];
    float m = fmaxf(fmaxf(l0, l1), fmaxf(l2, l3));
    float e0 = expf(l0 - m), e1 = expf(l1 - m);
    float e2 = expf(l2 - m), e3 = expf(l3 - m);
    float ep = (p == 0) ? e0 : (p == 1) ? e1 : (p == 2) ? e2 : e3;
    float wsm = ep / (e0 + e1 + e2 + e3);

    float gx = offq[h * 32 + (l * 4 + p) * 2 + 0];
    float gy = offq[h * 32 + (l * 4 + p) * 2 + 1];
    float s = 0.5f * (float)(Wl - 1);
    float px = fmaf(gx, s, s), py = fmaf(gy, s, s);
    float x0f = floorf(px), y0f = floorf(py);
    float wx = px - x0f, wy = py - y0f;
    int x0 = (int)x0f, y0 = (int)y0f;

    bool bx0 = (unsigned)x0 < (unsigned)Wl, bx1 = (unsigned)(x0 + 1) < (unsigned)Wl;
    bool by0 = (unsigned)y0 < (unsigned)Wl, by1 = (unsigned)(y0 + 1) < (unsigned)Wl;
    int x0c = min(max(x0, 0), Wl - 1), x1c = min(max(x0 + 1, 0), Wl - 1);
    int y0c = min(max(y0, 0), Wl - 1), y1c = min(max(y0 + 1, 0), Wl - 1);

    auto poff = [&](int xx, int yy) -> unsigned {
      return ((unsigned)((yy << (sh - 1)) + (xx >> 1)) << 10) |
             ((unsigned)(xx & 1) << 3);
    };

    float wxm = 1.f - wx, wym = 1.f - wy;
    float w00 = (bx0 & by0) ? wsm * wxm * wym : 0.f;
    float w01 = (bx1 & by0) ? wsm * wx  * wym : 0.f;
    float w10 = (bx0 & by1) ? wsm * wxm * wy  : 0.f;
    float w11 = (bx1 & by1) ? wsm * wx  * wy  : 0.f;

    unsigned* slot = cbase + (h * 17 + l * 4 + p) * 8;
    uint4 s0;
    s0.x = poff(x0c, y0c);
    s0.y = poff(x1c, y0c);
    s0.z = poff(x0c, y1c);
    s0.w = poff(x1c, y1c);
    *(uint4*)slot = s0;
    uint4 s1;
    s1.x = __builtin_bit_cast(unsigned, w00);
    s1.y = __builtin_bit_cast(unsigned, w01);
    s1.z = __builtin_bit_cast(unsigned, w10);
    s1.w = __builtin_bit_cast(unsigned, w11);
    *(uint4*)(slot + 4) = s1;
  }
  __syncthreads();

  // ---- phase 2: this wave's two levels
  const int h = lane >> 3, c4 = lane & 7;
  const unsigned laneoff = (unsigned)(h * 128 + c4 * 16);
  float4 acc = make_float4(0.f, 0.f, 0.f, 0.f);

#pragma unroll
  for (int dl = 0; dl < 2; ++dl) {
    const int l = 2 * w + dl;
    const char* lb = v + ((size_t)b * NV_ + LSc[l]) * 512;
    const unsigned* cb = cbase + (h * 17 + l * 4) * 8;
#pragma unroll
    for (int p = 0; p < 4; ++p) {
      uint4 s0 = *(const uint4*)(cb + p * 8);
      uint4 s1 = *(const uint4*)(cb + p * 8 + 4);
      float w00 = __builtin_bit_cast(float, s1.x);
      float w01 = __builtin_bit_cast(float, s1.y);
      float w10 = __builtin_bit_cast(float, s1.z);
      float w11 = __builtin_bit_cast(float, s1.w);

      uint2 r00 = *(const uint2*)(lb + (laneoff + s0.x));
      uint2 r01 = *(const uint2*)(lb + (laneoff + s0.y));
      uint2 r10 = *(const uint2*)(lb + (laneoff + s0.z));
      uint2 r11 = *(const uint2*)(lb + (laneoff + s0.w));

      acc.x += w00 * __builtin_bit_cast(float, r00.x << 16)
             + w01 * __builtin_bit_cast(float, r01.x << 16)
             + w10 * __builtin_bit_cast(float, r10.x << 16)
             + w11 * __builtin_bit_cast(float, r11.x << 16);
      acc.y += w00 * __builtin_bit_cast(float, r00.x & 0xFFFF0000u)
             + w01 * __builtin_bit_cast(float, r01.x & 0xFFFF0000u)
             + w10 * __builtin_bit_cast(float, r10.x & 0xFFFF0000u)
             + w11 * __builtin_bit_cast(float, r11.x & 0xFFFF0000u);
      acc.z += w00 * __builtin_bit_cast(float, r00.y << 16)
             + w01 * __builtin_bit_cast(float, r01.y << 16)
             + w10 * __builtin_bit_cast(float, r10.y << 16)
             + w11 * __builtin_bit_cast(float, r11.y << 16);
      acc.w += w00 * __builtin_bit_cast(float, r00.y & 0xFFFF0000u)
             + w01 * __builtin_bit_cast(float, r01.y & 0xFFFF0000u)
             + w10 * __builtin_bit_cast(float, r10.y & 0xFFFF0000u)
             + w11 * __builtin_bit_cast(float, r11.y & 0xFFFF0000u);
    }
  }

  // ---- phase 3: merge wave pairs via LDS (coeff is dead after barrier)
  __syncthreads();
  float4* red = (float4*)coeff;    // 4 q x 64 lanes x 16 B = 4096 B
  if (w == 1) red[wq * 64 + lane] = acc;
  __syncthreads();
  if (w == 0) {
    float4 o2 = red[wq * 64 + lane];
    acc.x += o2.x; acc.y += o2.y; acc.z += o2.z; acc.w += o2.w;
    ushort4 o;
    o.x = f2bf(acc.x); o.y = f2bf(acc.y); o.z = f2bf(acc.z); o.w = f2bf(acc.w);
    tmp4[(size_t)bq * 64 + lane] = o;
  }
}

// ---------------------------------------------------------------------------
extern "C" void kernel_launch(void* const* d_in, const int* in_sizes, int n_in,
                              void* d_out, int out_size, void* d_ws, size_t ws_size,
                              hipStream_t stream) {
  const float* query  = (const float*)d_in[0];
  // d_in[1] = key (unused)
  const float* value  = (const float*)d_in[2];
  const float* W_off  = (const float*)d_in[3];
  const float* b_off  = (const float*)d_in[4];
  const float* W_attn = (const float*)d_in[5];
  const float* b_attn = (const float*)d_in[6];
  const float* W_v    = (const float*)d_in[7];
  const float* b_v    = (const float*)d_in[8];
  const float* W_out  = (const float*)d_in[9];
  const float* b_out  = (const float*)d_in[10];
  float* out = (float*)d_out;

  char* p = (char*)d_ws;
  unsigned short* v_bf  = (unsigned short*)p; p += (size_t)MV * 256 * 2;   // 22.3 MB
  float*          off_w = (float*)p;          p += (size_t)MQ * 256 * 4;   // 20.5 MB
  float*          att_w = (float*)p;          p += (size_t)MQ * 128 * 4;   // 10.2 MB
  unsigned short* tmp_bf= (unsigned short*)p; p += (size_t)MQ * 256 * 2;   // 10.2 MB
  unsigned short* WvT   = (unsigned short*)p; p += 256 * 256 * 2;
  unsigned short* WoutT = (unsigned short*)p; p += 256 * 256 * 2;
  unsigned short* WqHi  = (unsigned short*)p; p += 384 * 256 * 2;
  unsigned short* WqLo  = (unsigned short*)p; p += 384 * 256 * 2;

  prep_weights<<<dim3(896), dim3(256), 0, stream>>>(
      W_v, W_attn, W_off, W_out, WvT, WoutT, WqHi, WqLo);

  // v = value @ W_v + b_v  (bf16 out, x-pair-packed layout via VPERM)
  gemm_mfma<1, unsigned short, true><<<dim3(MV / 128, 2), dim3(256), 0, stream>>>(
      value, WvT, nullptr, b_v, nullptr, v_bf, nullptr, MV, 256);

  // fused q projections: cols 0-255 -> off (3-term), 256-383 -> attn (1-term)
  gemm_mfma<3, float><<<dim3((MQ + 127) / 128, 3), dim3(256), 0, stream>>>(
      query, WqHi, WqLo, b_off, b_attn, off_w, att_w, MQ, 384);

  // bilinear sampling + softmax-weighted accumulation (2 waves / query)
  msda_sample7<<<dim3(MQ / 4), dim3(512), 0, stream>>>(
      (const char*)v_bf, off_w, att_w, (ushort4*)tmp_bf);

  // out = tmp @ W_out + b_out
  gemm_mfma<0, float><<<dim3((MQ + 127) / 128, 2), dim3(256), 0, stream>>>(
      tmp_bf, WoutT, nullptr, b_out, nullptr, out, nullptr, MQ, 256);
}

// Round 13
// 119.810 us; speedup vs baseline: 1.1070x; 1.0460x over previous
//
#include <hip/hip_runtime.h>
#include <math.h>

#define B_   2
#define NQ_  10000
#define NV_  21760
#define EMB  256
#define MQ   (B_*NQ_)   // 20000
#define MV   (B_*NV_)   // 43520

typedef short bf16x8 __attribute__((ext_vector_type(8)));
typedef float f32x4  __attribute__((ext_vector_type(4)));

__device__ constexpr int LSc[4] = {0, 16384, 20480, 21504};

__device__ __forceinline__ unsigned short f2bf(float x) {
  unsigned u = __builtin_bit_cast(unsigned, x);
  u += 0x7FFFu + ((u >> 16) & 1u);
  return (unsigned short)(u >> 16);
}
__device__ __forceinline__ float bf2f(unsigned short s) {
  return __builtin_bit_cast(float, (unsigned)s << 16);
}

// ---------------------------------------------------------------------------
// Weight prep (unchanged).
// ---------------------------------------------------------------------------
__global__ __launch_bounds__(256) void prep_weights(
    const float* __restrict__ Wv, const float* __restrict__ Wattn,
    const float* __restrict__ Woff, const float* __restrict__ Wout,
    unsigned short* __restrict__ WvT, unsigned short* __restrict__ WoutT,
    unsigned short* __restrict__ WqHi, unsigned short* __restrict__ WqLo) {
  int n = blockIdx.x;       // 0..895
  int k = threadIdx.x;      // 0..255
  if (n < 256) {
    WvT[n * 256 + k] = f2bf(Wv[k * 256 + n]);
  } else if (n < 512) {
    int c = n - 256;
    WoutT[c * 256 + k] = f2bf(Wout[k * 256 + c]);
  } else {
    int qr = n - 512;       // 0..383
    float x = (qr < 256) ? Woff[k * 256 + qr] : Wattn[k * 128 + (qr - 256)];
    unsigned short hi = f2bf(x);
    WqHi[qr * 256 + k] = hi;
    WqLo[qr * 256 + k] = f2bf(x - bf2f(hi));
  }
}

// ---------------------------------------------------------------------------
// MFMA GEMM. 128x128 tile, BK=32, 4 waves (2x2), 4x4 16x16x32 frags/wave.
// bf16 staging via global_load_lds(16B): linear LDS dest, pre-swizzled src
// (rule #21); ds_read_b128 side swizzle unchanged.
// MODE 0: A bf16, 1-term.   MODE 1: A fp32 (cvt in staging), 1-term.
// MODE 3: A fp32 split hi/lo in staging; 3-term for col0<256 (off cols),
//         1-term for col0>=256 (attn cols, bf16 out via C2).
// VPERM:  epilogue assembles the x-pair-packed bf16 v tile in LDS (32 KB)
//         then writes coalesced 64-B runs. Pair-block = 1024 B (2 pixels):
//         byte = h*128 + (d>>2)*16 + (x&1)*8 + (d&3)*2   [v7 8B-parity]
// ---------------------------------------------------------------------------
template <int MODE, typename OutT, bool VPERM = false>
__global__ __launch_bounds__(256) void gemm_mfma(
    const void* __restrict__ Aa,
    const unsigned short* __restrict__ Bt, const unsigned short* __restrict__ Bt2,
    const float* __restrict__ bias, const float* __restrict__ bias2,
    OutT* __restrict__ C, unsigned short* __restrict__ C2, int M, int N) {
  constexpr int BM = 128, BK = 32;
  constexpr int SMEM_SHORTS = (MODE == 3 || VPERM) ? 16384 : 8192;
  __shared__ unsigned short smem[SMEM_SHORTS];
  unsigned short* As  = smem;
  unsigned short* Bs  = smem + ((MODE == 3) ? 2 : 1) * BM * BK;
  unsigned short* As2 = smem + BM * BK;       // MODE3 only
  unsigned short* Bs2 = smem + 3 * BM * BK;   // MODE3 only

  const int tid = threadIdx.x;
  const int lane = tid & 63, wv = tid >> 6;
  const int wr = wv >> 1, wc = wv & 1;
  const int row0 = blockIdx.x * BM, col0 = blockIdx.y * BM;

  auto lds_addr = [](int row, int kslot) -> int {
    return row * 64 + ((kslot ^ ((row >> 1) & 3)) << 4);
  };

  // bf16 staging via global_load_lds(16B): linear LDS dest, pre-swizzled src.
  auto stage_bf = [&](unsigned short* dst, const unsigned short* src,
                      int rbase, int rmax, int kk) {
#pragma unroll
    for (int i = 0; i < 2; ++i) {
      int idx = tid + 256 * i;
      int row = idx >> 2, ks = idx & 3;
      int rg = min(rbase + row, rmax);
      int xorb = (row >> 1) & 3;
      const unsigned short* gp =
          src + (size_t)rg * 256 + kk + ((ks ^ xorb) << 3);
      unsigned short* lp = dst + (size_t)(wv * 64 + i * 256) * 8;
      __builtin_amdgcn_global_load_lds(
          (const __attribute__((address_space(1))) void*)gp,
          (__attribute__((address_space(3))) void*)lp, 16, 0, 0);
    }
  };
  auto stage_cvt = [&](unsigned short* dst, const float* src,
                       int rbase, int rmax, int kk) {
#pragma unroll
    for (int i = 0; i < 4; ++i) {
      int idx = tid + 256 * i;
      int row = idx >> 3, c4 = idx & 7;
      int rg = min(rbase + row, rmax);
      float4 vdat = *(const float4*)(src + (size_t)rg * 256 + kk + c4 * 4);
      ushort4 o;
      o.x = f2bf(vdat.x); o.y = f2bf(vdat.y);
      o.z = f2bf(vdat.z); o.w = f2bf(vdat.w);
      *(ushort4*)((char*)dst + lds_addr(row, c4 >> 1) + (c4 & 1) * 8) = o;
    }
  };
  auto stage_cvt2 = [&](unsigned short* dstH, unsigned short* dstL,
                        const float* src, int rbase, int rmax, int kk) {
#pragma unroll
    for (int i = 0; i < 4; ++i) {
      int idx = tid + 256 * i;
      int row = idx >> 3, c4 = idx & 7;
      int rg = min(rbase + row, rmax);
      float4 vdat = *(const float4*)(src + (size_t)rg * 256 + kk + c4 * 4);
      ushort4 hh, ll;
      hh.x = f2bf(vdat.x); ll.x = f2bf(vdat.x - bf2f(hh.x));
      hh.y = f2bf(vdat.y); ll.y = f2bf(vdat.y - bf2f(hh.y));
      hh.z = f2bf(vdat.z); ll.z = f2bf(vdat.z - bf2f(hh.z));
      hh.w = f2bf(vdat.w); ll.w = f2bf(vdat.w - bf2f(hh.w));
      int a = lds_addr(row, c4 >> 1) + (c4 & 1) * 8;
      *(ushort4*)((char*)dstH + a) = hh;
      *(ushort4*)((char*)dstL + a) = ll;
    }
  };

  const bool three_term = (MODE == 3) && (col0 < 256);

  f32x4 acc[4][4] = {};

  for (int kk = 0; kk < 256; kk += BK) {
    if (kk) __syncthreads();
    if constexpr (MODE == 1)
      stage_cvt(As, (const float*)Aa, row0, M - 1, kk);
    else if constexpr (MODE == 3) {
      if (three_term)
        stage_cvt2(As, As2, (const float*)Aa, row0, M - 1, kk);
      else
        stage_cvt(As, (const float*)Aa, row0, M - 1, kk);
    } else
      stage_bf(As, (const unsigned short*)Aa, row0, M - 1, kk);
    stage_bf(Bs, Bt, col0, N - 1, kk);
    if constexpr (MODE == 3)
      if (three_term) stage_bf(Bs2, Bt2, col0, N - 1, kk);
    __syncthreads();

    const int kslot = lane >> 4;
    bf16x8 af[4], bfr[4];
#pragma unroll
    for (int i = 0; i < 4; ++i) {
      int ra = wr * 64 + i * 16 + (lane & 15);
      af[i] = *(const bf16x8*)((const char*)As + lds_addr(ra, kslot));
      int rb = wc * 64 + i * 16 + (lane & 15);
      bfr[i] = *(const bf16x8*)((const char*)Bs + lds_addr(rb, kslot));
    }
#pragma unroll
    for (int mi = 0; mi < 4; ++mi)
#pragma unroll
      for (int ni = 0; ni < 4; ++ni)
        acc[mi][ni] = __builtin_amdgcn_mfma_f32_16x16x32_bf16(
            af[mi], bfr[ni], acc[mi][ni], 0, 0, 0);

    if constexpr (MODE == 3) {
      if (three_term) {
        bf16x8 af2[4], bfr2[4];
#pragma unroll
        for (int i = 0; i < 4; ++i) {
          int ra = wr * 64 + i * 16 + (lane & 15);
          af2[i] = *(const bf16x8*)((const char*)As2 + lds_addr(ra, kslot));
          int rb = wc * 64 + i * 16 + (lane & 15);
          bfr2[i] = *(const bf16x8*)((const char*)Bs2 + lds_addr(rb, kslot));
        }
#pragma unroll
        for (int mi = 0; mi < 4; ++mi)
#pragma unroll
          for (int ni = 0; ni < 4; ++ni) {
            acc[mi][ni] = __builtin_amdgcn_mfma_f32_16x16x32_bf16(
                af2[mi], bfr[ni], acc[mi][ni], 0, 0, 0);
            acc[mi][ni] = __builtin_amdgcn_mfma_f32_16x16x32_bf16(
                af[mi], bfr2[ni], acc[mi][ni], 0, 0, 0);
          }
      }
    }
  }

  // epilogue: D frag layout col=lane&15, row=(lane>>4)*4+reg  [m89-verified]
  if constexpr (VPERM) {
    float bb4[4];
#pragma unroll
    for (int ni = 0; ni < 4; ++ni)
      bb4[ni] = bias[col0 + wc * 64 + ni * 16 + (lane & 15)];
    __syncthreads();                 // As/Bs dead; reuse the 32 KB
    unsigned short* pbuf = smem;
#pragma unroll
    for (int mi = 0; mi < 4; ++mi) {
#pragma unroll
      for (int r = 0; r < 4; ++r) {
        int lr = wr * 64 + mi * 16 + ((lane >> 4) << 2) + r;  // local row
        int pb = lr >> 1, par = lr & 1;
#pragma unroll
        for (int ni = 0; ni < 4; ++ni) {
          int lc = wc * 64 + ni * 16 + (lane & 15);
          float val = acc[mi][ni][r] + bb4[ni];
          int hl = lc >> 5, d = lc & 31;
          int off = pb * 512 + hl * 128 + ((d >> 2) << 4) + (par << 3) +
                    ((d & 3) << 1);
          *(unsigned short*)((char*)pbuf + off) = f2bf(val);
        }
      }
    }
    __syncthreads();
    // coalesced write-out: 64 pair-blocks x 512 B (this block's 4 heads)
    int pix0 = row0, bb2 = 0;
    if (pix0 >= NV_) { bb2 = 1; pix0 -= NV_; }
    int lvl = (pix0 >= 16384) + (pix0 >= 20480) + (pix0 >= 21504);
    int rel0 = pix0 - LSc[lvl];
    char* dst = (char*)C + ((size_t)bb2 * NV_ + LSc[lvl]) * 512 +
                (size_t)(rel0 >> 1) * 1024 + (size_t)(col0 >> 5) * 128;
    int pb = tid >> 2, q = tid & 3;
#pragma unroll
    for (int i = 0; i < 8; ++i) {
      int u = q * 16 + i * 64;
      uint4 vd = *(const uint4*)((const char*)pbuf + pb * 512 + u);
      *(uint4*)(dst + (size_t)pb * 1024 + u) = vd;
    }
  } else {
#pragma unroll
    for (int ni = 0; ni < 4; ++ni) {
      int gcol = col0 + wc * 64 + ni * 16 + (lane & 15);
      float bb = (MODE == 3 && gcol >= 256) ? bias2[gcol - 256] : bias[gcol];
#pragma unroll
      for (int mi = 0; mi < 4; ++mi) {
        int rowbase = row0 + wr * 64 + mi * 16 + ((lane >> 4) << 2);
        f32x4 a = acc[mi][ni];
#pragma unroll
        for (int r = 0; r < 4; ++r) {
          int row = rowbase + r;
          if (row < M) {
            float val = a[r] + bb;
            if constexpr (MODE == 3) {
              if (gcol >= 256)
                C2[(size_t)row * 128 + (gcol - 256)] = f2bf(val);  // attn bf16
              else
                ((float*)C)[(size_t)row * 256 + gcol] = val;
            } else if constexpr (sizeof(OutT) == 2) {
              C[(size_t)row * N + gcol] = (OutT)f2bf(val);
            } else {
              C[(size_t)row * N + gcol] = (OutT)val;
            }
          }
        }
      }
    }
  }
}

// ---------------------------------------------------------------------------
// Sampling v7b: 256-thread block = 2 queries x 2 waves; wave w owns levels
// {2w, 2w+1}. Phase 1: one (h,l,p) combo per lane (attn logits read as
// bf16, one 8-B load + 4 bit-ops) -> skewed 32-B LDS slot. Phase 2: 16 x
// 8-B gathers per level (pair-packed bf16 v). Phase 3: LDS wave-pair merge.
// ---------------------------------------------------------------------------
__global__ __launch_bounds__(256) void msda_sample7(
    const char* __restrict__ v,                    // pair-packed bf16
    const float* __restrict__ off,                 // (MQ, 256) fp32
    const unsigned short* __restrict__ attnlg,     // (MQ, 128) bf16
    ushort4* __restrict__ tmp4) {                  // (MQ, 64) bf16 (h,d)
  __shared__ unsigned coeff[2 * 136 * 8];   // 8704 B; first 2 KB reused
  const int tid = threadIdx.x;
  const int lane = tid & 63;
  const int wid = tid >> 6;        // 0..3
  const int wq = wid >> 1;         // query-in-block 0..1
  const int w = wid & 1;           // level-half
  const int bq = blockIdx.x * 2 + wq;
  const int b = (blockIdx.x * 2) / NQ_;   // block-uniform (no straddle)

  unsigned* cbase = coeff + wq * (136 * 8);
  const float* offq = off + (size_t)bq * 256;
  const unsigned short* attq = attnlg + (size_t)bq * 128;

  // ---- phase 1: one combo per lane
  {
    int h = lane >> 3, dl = (lane >> 2) & 1, p = lane & 3;
    int l = 2 * w + dl;
    int Wl = 128 >> l, sh = 7 - l;

    uint2 lg = *(const uint2*)(attq + h * 16 + l * 4);
    float l0 = __builtin_bit_cast(float, lg.x << 16);
    float l1 = __builtin_bit_cast(float, lg.x & 0xFFFF0000u);
    float l2 = __builtin_bit_cast(float, lg.y << 16);
    float l3 = __builtin_bit_cast(float, lg.y & 0xFFFF0000u);
    float m = fmaxf(fmaxf(l0, l1), fmaxf(l2, l3));
    float e0 = expf(l0 - m), e1 = expf(l1 - m);
    float e2 = expf(l2 - m), e3 = expf(l3 - m);
    float ep = (p == 0) ? e0 : (p == 1) ? e1 : (p == 2) ? e2 : e3;
    float wsm = ep / (e0 + e1 + e2 + e3);

    float gx = offq[h * 32 + (l * 4 + p) * 2 + 0];
    float gy = offq[h * 32 + (l * 4 + p) * 2 + 1];
    float s = 0.5f * (float)(Wl - 1);
    float px = fmaf(gx, s, s), py = fmaf(gy, s, s);
    float x0f = floorf(px), y0f = floorf(py);
    float wx = px - x0f, wy = py - y0f;
    int x0 = (int)x0f, y0 = (int)y0f;

    bool bx0 = (unsigned)x0 < (unsigned)Wl, bx1 = (unsigned)(x0 + 1) < (unsigned)Wl;
    bool by0 = (unsigned)y0 < (unsigned)Wl, by1 = (unsigned)(y0 + 1) < (unsigned)Wl;
    int x0c = min(max(x0, 0), Wl - 1), x1c = min(max(x0 + 1, 0), Wl - 1);
    int y0c = min(max(y0, 0), Wl - 1), y1c = min(max(y0 + 1, 0), Wl - 1);

    auto poff = [&](int xx, int yy) -> unsigned {
      return ((unsigned)((yy << (sh - 1)) + (xx >> 1)) << 10) |
             ((unsigned)(xx & 1) << 3);
    };

    float wxm = 1.f - wx, wym = 1.f - wy;
    float w00 = (bx0 & by0) ? wsm * wxm * wym : 0.f;
    float w01 = (bx1 & by0) ? wsm * wx  * wym : 0.f;
    float w10 = (bx0 & by1) ? wsm * wxm * wy  : 0.f;
    float w11 = (bx1 & by1) ? wsm * wx  * wy  : 0.f;

    unsigned* slot = cbase + (h * 17 + l * 4 + p) * 8;
    uint4 s0;
    s0.x = poff(x0c, y0c);
    s0.y = poff(x1c, y0c);
    s0.z = poff(x0c, y1c);
    s0.w = poff(x1c, y1c);
    *(uint4*)slot = s0;
    uint4 s1;
    s1.x = __builtin_bit_cast(unsigned, w00);
    s1.y = __builtin_bit_cast(unsigned, w01);
    s1.z = __builtin_bit_cast(unsigned, w10);
    s1.w = __builtin_bit_cast(unsigned, w11);
    *(uint4*)(slot + 4) = s1;
  }
  __syncthreads();

  // ---- phase 2: this wave's two levels
  const int h = lane >> 3, c4 = lane & 7;
  const unsigned laneoff = (unsigned)(h * 128 + c4 * 16);
  float4 acc = make_float4(0.f, 0.f, 0.f, 0.f);

#pragma unroll
  for (int dl = 0; dl < 2; ++dl) {
    const int l = 2 * w + dl;
    const char* lb = v + ((size_t)b * NV_ + LSc[l]) * 512;
    const unsigned* cb = cbase + (h * 17 + l * 4) * 8;
#pragma unroll
    for (int p = 0; p < 4; ++p) {
      uint4 s0 = *(const uint4*)(cb + p * 8);
      uint4 s1 = *(const uint4*)(cb + p * 8 + 4);
      float w00 = __builtin_bit_cast(float, s1.x);
      float w01 = __builtin_bit_cast(float, s1.y);
      float w10 = __builtin_bit_cast(float, s1.z);
      float w11 = __builtin_bit_cast(float, s1.w);

      uint2 r00 = *(const uint2*)(lb + (laneoff + s0.x));
      uint2 r01 = *(const uint2*)(lb + (laneoff + s0.y));
      uint2 r10 = *(const uint2*)(lb + (laneoff + s0.z));
      uint2 r11 = *(const uint2*)(lb + (laneoff + s0.w));

      acc.x += w00 * __builtin_bit_cast(float, r00.x << 16)
             + w01 * __builtin_bit_cast(float, r01.x << 16)
             + w10 * __builtin_bit_cast(float, r10.x << 16)
             + w11 * __builtin_bit_cast(float, r11.x << 16);
      acc.y += w00 * __builtin_bit_cast(float, r00.x & 0xFFFF0000u)
             + w01 * __builtin_bit_cast(float, r01.x & 0xFFFF0000u)
             + w10 * __builtin_bit_cast(float, r10.x & 0xFFFF0000u)
             + w11 * __builtin_bit_cast(float, r11.x & 0xFFFF0000u);
      acc.z += w00 * __builtin_bit_cast(float, r00.y << 16)
             + w01 * __builtin_bit_cast(float, r01.y << 16)
             + w10 * __builtin_bit_cast(float, r10.y << 16)
             + w11 * __builtin_bit_cast(float, r11.y << 16);
      acc.w += w00 * __builtin_bit_cast(float, r00.y & 0xFFFF0000u)
             + w01 * __builtin_bit_cast(float, r01.y & 0xFFFF0000u)
             + w10 * __builtin_bit_cast(float, r10.y & 0xFFFF0000u)
             + w11 * __builtin_bit_cast(float, r11.y & 0xFFFF0000u);
    }
  }

  // ---- phase 3: merge wave pairs via LDS (coeff dead after barrier)
  __syncthreads();
  float4* red = (float4*)coeff;    // 2 q x 64 lanes x 16 B = 2048 B
  if (w == 1) red[wq * 64 + lane] = acc;
  __syncthreads();
  if (w == 0) {
    float4 o2 = red[wq * 64 + lane];
    acc.x += o2.x; acc.y += o2.y; acc.z += o2.z; acc.w += o2.w;
    ushort4 o;
    o.x = f2bf(acc.x); o.y = f2bf(acc.y); o.z = f2bf(acc.z); o.w = f2bf(acc.w);
    tmp4[(size_t)bq * 64 + lane] = o;
  }
}

// ---------------------------------------------------------------------------
extern "C" void kernel_launch(void* const* d_in, const int* in_sizes, int n_in,
                              void* d_out, int out_size, void* d_ws, size_t ws_size,
                              hipStream_t stream) {
  const float* query  = (const float*)d_in[0];
  // d_in[1] = key (unused)
  const float* value  = (const float*)d_in[2];
  const float* W_off  = (const float*)d_in[3];
  const float* b_off  = (const float*)d_in[4];
  const float* W_attn = (const float*)d_in[5];
  const float* b_attn = (const float*)d_in[6];
  const float* W_v    = (const float*)d_in[7];
  const float* b_v    = (const float*)d_in[8];
  const float* W_out  = (const float*)d_in[9];
  const float* b_out  = (const float*)d_in[10];
  float* out = (float*)d_out;

  char* p = (char*)d_ws;
  unsigned short* v_bf  = (unsigned short*)p; p += (size_t)MV * 256 * 2;   // 22.3 MB
  float*          off_w = (float*)p;          p += (size_t)MQ * 256 * 4;   // 20.5 MB
  unsigned short* att_w = (unsigned short*)p; p += (size_t)MQ * 128 * 2;   //  5.1 MB
  unsigned short* tmp_bf= (unsigned short*)p; p += (size_t)MQ * 256 * 2;   // 10.2 MB
  unsigned short* WvT   = (unsigned short*)p; p += 256 * 256 * 2;
  unsigned short* WoutT = (unsigned short*)p; p += 256 * 256 * 2;
  unsigned short* WqHi  = (unsigned short*)p; p += 384 * 256 * 2;
  unsigned short* WqLo  = (unsigned short*)p; p += 384 * 256 * 2;

  prep_weights<<<dim3(896), dim3(256), 0, stream>>>(
      W_v, W_attn, W_off, W_out, WvT, WoutT, WqHi, WqLo);

  // v = value @ W_v + b_v  (bf16, pair-packed, LDS-coalesced epilogue)
  gemm_mfma<1, unsigned short, true><<<dim3(MV / 128, 2), dim3(256), 0, stream>>>(
      value, WvT, nullptr, b_v, nullptr, v_bf, nullptr, MV, 256);

  // fused q projections: cols 0-255 -> off fp32 (3-term), 256-383 -> attn bf16
  gemm_mfma<3, float><<<dim3((MQ + 127) / 128, 3), dim3(256), 0, stream>>>(
      query, WqHi, WqLo, b_off, b_attn, off_w, att_w, MQ, 384);

  // bilinear sampling + softmax-weighted accumulation (2 waves / query)
  msda_sample7<<<dim3(MQ / 2), dim3(256), 0, stream>>>(
      (const char*)v_bf, off_w, att_w, (ushort4*)tmp_bf);

  // out = tmp @ W_out + b_out
  gemm_mfma<0, float><<<dim3((MQ + 127) / 128, 2), dim3(256), 0, stream>>>(
      tmp_bf, WoutT, nullptr, b_out, nullptr, out, nullptr, MQ, 256);
}